// Round 2
// baseline (3373.528 us; speedup 1.0000x reference)
//
#include <hip/hip_runtime.h>

// ---------------------------------------------------------------------------
// TextClassification: embedding -> LSTM(2048 steps) -> linear head
// V=50257 D=256 H=256 O=10 L=2048 N=64
//
// ws is only 256 MiB -> pipeline runs in 2 chunks of 1024 steps:
//   gemm(chunk) writes gate pre-activations for 1024 steps (134 MB fp16),
//   lstm(chunk) consumes them, carrying h/c (f32) in a small state buffer.
//
// Phase A: fp16 MFMA GEMM  gates[m][p] = emb[x[m]] . Wx[p] + (bx[p]+bh[p])
// Phase B: 64 persistent blocks (1 CU per chain). Per-thread weight slice
//          (1 KB) split: 8 k-chunks in VGPRs, 4 in LDS (128 KB), 4 streamed
//          from L2. fdot2 f32-accumulate. Gates prefetched 1 step ahead.
// Phase C: folded into last lstm chunk tail.
// ---------------------------------------------------------------------------

using half_t  = _Float16;
using half2_t = __attribute__((ext_vector_type(2))) _Float16;
using half8_t = __attribute__((ext_vector_type(8))) _Float16;
using f32x4   = __attribute__((ext_vector_type(4))) float;

#define L_SEQ   2048
#define CHUNK_L 1024
#define NB      64
#define DIM     256
#define P4      1024                 // 4 gates * H
#define CM      (CHUNK_L * NB)       // 65536 rows per chunk

// workspace layout (bytes), all 16B-aligned
#define OFF_GATES 0ull
#define SZ_GATES  ((unsigned long long)CM * P4 * 2)        // 134217728
#define OFF_EMBH  (OFF_GATES + SZ_GATES)
#define SZ_EMBH   (50257ull * 256 * 2)                     // 25731584
#define OFF_WX    (OFF_EMBH + SZ_EMBH)
#define SZ_WX     (1024ull * 256 * 2)
#define OFF_WH    (OFF_WX + SZ_WX)
#define SZ_WH     (1024ull * 256 * 2)
#define OFF_B4    (OFF_WH + SZ_WH)
#define SZ_B4     (1024ull * 4)
#define OFF_ST    (OFF_B4 + SZ_B4)
#define SZ_ST     (2ull * NB * DIM * 4)                    // h,c f32
#define WS_NEED   (OFF_ST + SZ_ST)                         // ~161.1 MB

// ---------------- helpers ----------------
__device__ __forceinline__ float sigm(float x) {
  x = fminf(fmaxf(x, -30.f), 30.f);
  return 1.f / (1.f + __expf(-x));
}
__device__ __forceinline__ float tanh_(float x) {
  x = fminf(fmaxf(x, -15.f), 15.f);
  float t = __expf(2.f * x);
  return (t - 1.f) / (t + 1.f);
}
__device__ __forceinline__ float dot8(half8_t w, half8_t h, float acc) {
  acc = __builtin_amdgcn_fdot2((half2_t)__builtin_shufflevector(w, w, 0, 1),
                               (half2_t)__builtin_shufflevector(h, h, 0, 1), acc, false);
  acc = __builtin_amdgcn_fdot2((half2_t)__builtin_shufflevector(w, w, 2, 3),
                               (half2_t)__builtin_shufflevector(h, h, 2, 3), acc, false);
  acc = __builtin_amdgcn_fdot2((half2_t)__builtin_shufflevector(w, w, 4, 5),
                               (half2_t)__builtin_shufflevector(h, h, 4, 5), acc, false);
  acc = __builtin_amdgcn_fdot2((half2_t)__builtin_shufflevector(w, w, 6, 7),
                               (half2_t)__builtin_shufflevector(h, h, 6, 7), acc, false);
  return acc;
}

// ---------------- kernels ----------------
__global__ void ws_too_small_kernel(float* out, float sz) {
  if (threadIdx.x == 0 && blockIdx.x == 0) out[0] = sz;
}

__global__ void cvt_emb_kernel(const float* __restrict__ src, half_t* __restrict__ dst,
                               int total8) {
  int i = blockIdx.x * blockDim.x + threadIdx.x;
  if (i >= total8) return;
  const float4* s = (const float4*)src + (size_t)i * 2;
  float4 a = s[0], b = s[1];
  half8_t o;
  o[0] = (half_t)a.x; o[1] = (half_t)a.y; o[2] = (half_t)a.z; o[3] = (half_t)a.w;
  o[4] = (half_t)b.x; o[5] = (half_t)b.y; o[6] = (half_t)b.z; o[7] = (half_t)b.w;
  *((half8_t*)dst + i) = o;
}

// Wx4h[p][k] row-major fp16 (p = gate*256+h, k = d)
// Wh4c[(k>>3)][p][k&7] fp16 (16B chunk per (k-chunk, p); lane-coalesced)
// b4[p] = b_input[p] + b_hidden[p]
__global__ void pack_w_kernel(const float* __restrict__ Wii, const float* __restrict__ Whi,
                              const float* __restrict__ Wif, const float* __restrict__ Whf,
                              const float* __restrict__ Wig, const float* __restrict__ Whg,
                              const float* __restrict__ Wio, const float* __restrict__ Who,
                              const float* __restrict__ bii, const float* __restrict__ bhi,
                              const float* __restrict__ bif, const float* __restrict__ bhf,
                              const float* __restrict__ big_, const float* __restrict__ bhg,
                              const float* __restrict__ bio, const float* __restrict__ bho,
                              half_t* __restrict__ Wx4h, half_t* __restrict__ Wh4c,
                              float* __restrict__ b4) {
  int p = blockIdx.x;   // 0..1023
  int k = threadIdx.x;  // 0..255
  int g = p >> 8, h = p & 255;
  const float* Wx = g == 0 ? Wii : g == 1 ? Wif : g == 2 ? Wig : Wio;
  const float* Wh = g == 0 ? Whi : g == 1 ? Whf : g == 2 ? Whg : Who;
  Wx4h[(size_t)p * DIM + k] = (half_t)Wx[h * DIM + k];
  Wh4c[((size_t)(k >> 3) * P4 + p) * 8 + (k & 7)] = (half_t)Wh[h * DIM + k];
  if (k == 0) {
    const float* bx = g == 0 ? bii : g == 1 ? bif : g == 2 ? big_ : bio;
    const float* bh = g == 0 ? bhi : g == 1 ? bhf : g == 2 ? bhg : bho;
    b4[p] = bx[h] + bh[h];
  }
}

// Phase A GEMM: gates[CM][P4] = gather(embh, xc)[CM][256] @ Wx4h^T + b4
// 128x128 tile, BK=32, 4 waves (2x2 of 64x64), mfma_f32_16x16x32_f16.
#define BK   32
#define LSTR 40  // LDS row stride in halfs
__global__ __launch_bounds__(256) void gemm_gates_kernel(
    const half_t* __restrict__ embh, const int* __restrict__ xc,
    const half_t* __restrict__ Wx4h, const float* __restrict__ b4,
    half_t* __restrict__ gates) {
  __shared__ __align__(16) half_t As[128 * LSTR];
  __shared__ __align__(16) half_t Ws[128 * LSTR];
  const int tid  = threadIdx.x;
  const int lane = tid & 63;
  const int wave = tid >> 6;
  const int wm = wave >> 1, wn = wave & 1;
  const int M0 = blockIdx.x * 128;
  const int P0 = blockIdx.y * 128;
  const int r0 = tid >> 2, s0 = tid & 3;  // staging: 2 rows/thread, 16B seg each

  const size_t arow0 = (size_t)xc[M0 + r0] * DIM;
  const size_t arow1 = (size_t)xc[M0 + 64 + r0] * DIM;
  const size_t wrow0 = (size_t)(P0 + r0) * DIM;
  const size_t wrow1 = (size_t)(P0 + 64 + r0) * DIM;

  f32x4 acc[4][4] = {};
  const int fr = lane & 15;    // fragment row/col within 16x16
  const int kq = lane >> 4;    // k-quarter: k = kq*8 + j

  for (int kt = 0; kt < 8; ++kt) {
    const int k0 = kt * BK;
    half8_t a0 = *(const half8_t*)(embh + arow0 + k0 + s0 * 8);
    half8_t a1 = *(const half8_t*)(embh + arow1 + k0 + s0 * 8);
    half8_t w0 = *(const half8_t*)(Wx4h + wrow0 + k0 + s0 * 8);
    half8_t w1 = *(const half8_t*)(Wx4h + wrow1 + k0 + s0 * 8);
    __syncthreads();  // previous iter's LDS reads complete
    *(half8_t*)(As + r0 * LSTR + s0 * 8)        = a0;
    *(half8_t*)(As + (r0 + 64) * LSTR + s0 * 8) = a1;
    *(half8_t*)(Ws + r0 * LSTR + s0 * 8)        = w0;
    *(half8_t*)(Ws + (r0 + 64) * LSTR + s0 * 8) = w1;
    __syncthreads();
    half8_t af[4], bf[4];
#pragma unroll
    for (int mi = 0; mi < 4; ++mi)
      af[mi] = *(const half8_t*)(As + (wm * 64 + mi * 16 + fr) * LSTR + kq * 8);
#pragma unroll
    for (int ni = 0; ni < 4; ++ni)
      bf[ni] = *(const half8_t*)(Ws + (wn * 64 + ni * 16 + fr) * LSTR + kq * 8);
#pragma unroll
    for (int mi = 0; mi < 4; ++mi)
#pragma unroll
      for (int ni = 0; ni < 4; ++ni)
        acc[mi][ni] = __builtin_amdgcn_mfma_f32_16x16x32_f16(af[mi], bf[ni], acc[mi][ni], 0, 0, 0);
  }
  // D layout: col = lane&15, row = 4*(lane>>4) + r   [m89-verified]
  const int rbase = (lane >> 4) * 4;
#pragma unroll
  for (int ni = 0; ni < 4; ++ni) {
    const int p = P0 + wn * 64 + ni * 16 + fr;
    const float bias = b4[p];
#pragma unroll
    for (int mi = 0; mi < 4; ++mi) {
      const int m = M0 + wm * 64 + mi * 16 + rbase;
#pragma unroll
      for (int r = 0; r < 4; ++r)
        gates[(size_t)(m + r) * P4 + p] = (half_t)(acc[mi][ni][r] + bias);
    }
  }
}

// Phase B: one block per chain n. 512 threads: j = tid&255 (hidden unit),
// kh = tid>>8 splits the K=256 dot 2-way (thread k-range = [kh*128, kh*128+128)).
// Per-thread weights (64 x half8): kc 0..7 in VGPRs, 8..11 in LDS, 12..15 from L2.
__global__ __launch_bounds__(512, 2) void lstm_kernel(
    const half_t* __restrict__ gates, const half_t* __restrict__ Wh4c,
    const float* __restrict__ Wout, const float* __restrict__ bout,
    float* __restrict__ out, float* __restrict__ state,
    int first, int last) {
  const int n   = blockIdx.x;
  const int tid = threadIdx.x;
  const int j   = tid & 255;
  const int kh  = tid >> 8;
  __shared__ __align__(16) half_t wlds[8][P4][8];  // 128 KB weight cache
  __shared__ half_t hbuf[2][DIM];
  __shared__ float  partial[4][DIM];
  __shared__ float  hfin[DIM];

  const half8_t* W8 = (const half8_t*)Wh4c;
  // LDS cache fill: slot s holds kc = (s>>2)*16 + 8 + (s&3)  (kc 8..11 / 24..27)
  for (int i = tid; i < 8192; i += 512) {
    const int slot = i >> 10, p = i & 1023;
    const int kc = (slot >> 2) * 16 + 8 + (slot & 3);
    *(half8_t*)wlds[slot][p] = W8[kc * P4 + p];
  }
  // register-resident weights: this thread's kc0..kc0+7
  const int kc0 = kh * 16;
  const int b0 = j, b1 = 256 + j, b2 = 512 + j, b3 = 768 + j;
  half8_t wreg[8][4];
#pragma unroll
  for (int kc = 0; kc < 8; ++kc) {
    wreg[kc][0] = W8[(kc0 + kc) * P4 + b0];
    wreg[kc][1] = W8[(kc0 + kc) * P4 + b1];
    wreg[kc][2] = W8[(kc0 + kc) * P4 + b2];
    wreg[kc][3] = W8[(kc0 + kc) * P4 + b3];
  }

  float c = 0.f, hkeep = 0.f;
  if (kh == 0) {
    float h0 = 0.f;
    if (!first) { h0 = state[n * DIM + j]; c = state[NB * DIM + n * DIM + j]; }
    hbuf[0][j] = (half_t)h0;
    hbuf[1][j] = (half_t)0.f;
    hkeep = h0;
  }
  __syncthreads();

  // gates prefetch (1 step ahead)
  const half_t* gbase = gates + (size_t)n * P4;
  half_t g0 = (half_t)0.f, g1 = g0, g2 = g0, g3 = g0;
  if (kh == 0) { g0 = gbase[b0]; g1 = gbase[b1]; g2 = gbase[b2]; g3 = gbase[b3]; }

#pragma unroll 1
  for (int l = 0; l < CHUNK_L; ++l) {
    float a0 = 0.f, a1 = 0.f, a2 = 0.f, a3 = 0.f;
    if (kh == 0) { a0 = (float)g0; a1 = (float)g1; a2 = (float)g2; a3 = (float)g3; }
    const half8_t* hp = (const half8_t*)hbuf[l & 1] + kc0;
    // registers: kc 0..7
#pragma unroll
    for (int kc = 0; kc < 8; ++kc) {
      const half8_t h8 = hp[kc];
      a0 = dot8(wreg[kc][0], h8, a0);
      a1 = dot8(wreg[kc][1], h8, a1);
      a2 = dot8(wreg[kc][2], h8, a2);
      a3 = dot8(wreg[kc][3], h8, a3);
    }
    // LDS: kc 8..11
#pragma unroll
    for (int s = 0; s < 4; ++s) {
      const half8_t h8 = hp[8 + s];
      const int slot = kh * 4 + s;
      a0 = dot8(*(const half8_t*)wlds[slot][b0], h8, a0);
      a1 = dot8(*(const half8_t*)wlds[slot][b1], h8, a1);
      a2 = dot8(*(const half8_t*)wlds[slot][b2], h8, a2);
      a3 = dot8(*(const half8_t*)wlds[slot][b3], h8, a3);
    }
    // global (L2-resident): kc 12..15
#pragma unroll
    for (int s = 0; s < 4; ++s) {
      const half8_t h8 = hp[12 + s];
      const half8_t* wp = W8 + (size_t)(kc0 + 12 + s) * P4;
      a0 = dot8(wp[b0], h8, a0);
      a1 = dot8(wp[b1], h8, a1);
      a2 = dot8(wp[b2], h8, a2);
      a3 = dot8(wp[b3], h8, a3);
    }
    // prefetch next step's gates (read past end of chunk is harmless, in-ws)
    if (kh == 0) {
      const half_t* gp2 = gbase + (size_t)(l + 1) * NB * P4;
      g0 = gp2[b0]; g1 = gp2[b1]; g2 = gp2[b2]; g3 = gp2[b3];
    } else {
      partial[0][j] = a0; partial[1][j] = a1; partial[2][j] = a2; partial[3][j] = a3;
    }
    __syncthreads();
    if (kh == 0) {
      a0 += partial[0][j]; a1 += partial[1][j]; a2 += partial[2][j]; a3 += partial[3][j];
      const float it = sigm(a0), ft = sigm(a1), gt = tanh_(a2), ot = sigm(a3);
      c = ft * c + it * gt;
      const float h = ot * tanh_(c);
      hbuf[(l + 1) & 1][j] = (half_t)h;
      hkeep = h;
    }
    __syncthreads();
  }
  if (kh == 0) {
    if (!last) { state[n * DIM + j] = hkeep; state[NB * DIM + n * DIM + j] = c; }
    hfin[j] = hkeep;
  }
  __syncthreads();
  if (last && tid < 10) {
    float s = bout[tid];
    const float* wrow = Wout + tid * DIM;
#pragma unroll 4
    for (int k = 0; k < DIM; ++k) s += hfin[k] * wrow[k];
    out[n * 10 + tid] = s;
  }
}

// ---------------- launch ----------------
extern "C" void kernel_launch(void* const* d_in, const int* in_sizes, int n_in,
                              void* d_out, int out_size, void* d_ws, size_t ws_size,
                              hipStream_t stream) {
  const int*   x    = (const int*)d_in[0];
  const float* emb  = (const float*)d_in[1];
  const float* Wii  = (const float*)d_in[2];  const float* bii = (const float*)d_in[3];
  const float* Whi  = (const float*)d_in[4];  const float* bhi = (const float*)d_in[5];
  const float* Wif  = (const float*)d_in[6];  const float* bif = (const float*)d_in[7];
  const float* Whf  = (const float*)d_in[8];  const float* bhf = (const float*)d_in[9];
  const float* Wig  = (const float*)d_in[10]; const float* big_ = (const float*)d_in[11];
  const float* Whg  = (const float*)d_in[12]; const float* bhg = (const float*)d_in[13];
  const float* Wio  = (const float*)d_in[14]; const float* bio = (const float*)d_in[15];
  const float* Who  = (const float*)d_in[16]; const float* bho = (const float*)d_in[17];
  const float* Wout = (const float*)d_in[18]; const float* bout = (const float*)d_in[19];
  float* out = (float*)d_out;

  if (ws_size < WS_NEED) {  // fail loudly but safely: absmax will show ws_size
    hipLaunchKernelGGL(ws_too_small_kernel, dim3(1), dim3(64), 0, stream, out, (float)ws_size);
    return;
  }
  char* ws = (char*)d_ws;
  half_t* gates = (half_t*)(ws + OFF_GATES);
  half_t* embh  = (half_t*)(ws + OFF_EMBH);
  half_t* Wx4h  = (half_t*)(ws + OFF_WX);
  half_t* Wh4c  = (half_t*)(ws + OFF_WH);
  float*  b4    = (float*)(ws + OFF_B4);
  float*  state = (float*)(ws + OFF_ST);

  const int total8 = 50257 * 32;  // V*D/8
  hipLaunchKernelGGL(cvt_emb_kernel, dim3((total8 + 255) / 256), dim3(256), 0, stream,
                     emb, embh, total8);
  hipLaunchKernelGGL(pack_w_kernel, dim3(1024), dim3(256), 0, stream,
                     Wii, Whi, Wif, Whf, Wig, Whg, Wio, Who,
                     bii, bhi, bif, bhf, big_, bhg, bio, bho,
                     Wx4h, Wh4c, b4);
  // chunk 0: steps [0, 1024)
  hipLaunchKernelGGL(gemm_gates_kernel, dim3(CM / 128, P4 / 128), dim3(256), 0, stream,
                     embh, x, Wx4h, b4, gates);
  hipLaunchKernelGGL(lstm_kernel, dim3(NB), dim3(512), 0, stream,
                     gates, Wh4c, Wout, bout, out, state, 1, 0);
  // chunk 1: steps [1024, 2048)
  hipLaunchKernelGGL(gemm_gates_kernel, dim3(CM / 128, P4 / 128), dim3(256), 0, stream,
                     embh, x + (size_t)CHUNK_L * NB, Wx4h, b4, gates);
  hipLaunchKernelGGL(lstm_kernel, dim3(NB), dim3(512), 0, stream,
                     gates, Wh4c, Wout, bout, out, state, 0, 1);
}

// Round 3
// 3241.381 us; speedup vs baseline: 1.0408x; 1.0408x over previous
//
#include <hip/hip_runtime.h>

// ---------------------------------------------------------------------------
// TextClassification: embedding -> LSTM(2048 steps) -> linear head
// V=50257 D=256 H=256 O=10 L=2048 N=64
//
// ws is 256 MiB -> pipeline runs in 2 chunks of 1024 steps:
//   gemm(chunk) writes gate pre-activations for 1024 steps (134 MB fp16),
//   lstm(chunk) consumes them, carrying h/c (f32) in a small state buffer.
//
// Phase A: fp16 MFMA GEMM  gates[m][p] = emb[x[m]] . Wx[p] + (bx[p]+bh[p])
// Phase B: 64 persistent blocks (1 CU per chain). Per-thread weight slice
//          (1 KB): 12 k-chunks pinned in VGPRs (192 regs, asm-pinned so the
//          compiler cannot sink the loads back into the loop - round-2 showed
//          VGPR=120 i.e. it had been re-streaming 384 KB/step from L2),
//          4 k-chunks in a 128 KB LDS cache. Zero per-step weight traffic.
// Phase C: folded into last lstm chunk tail.
// ---------------------------------------------------------------------------

using half_t  = _Float16;
using half2_t = __attribute__((ext_vector_type(2))) _Float16;
using half8_t = __attribute__((ext_vector_type(8))) _Float16;
using f32x4   = __attribute__((ext_vector_type(4))) float;

#define L_SEQ   2048
#define CHUNK_L 1024
#define NB      64
#define DIM     256
#define P4      1024                 // 4 gates * H
#define CM      (CHUNK_L * NB)       // 65536 rows per chunk

// workspace layout (bytes), all 16B-aligned
#define OFF_GATES 0ull
#define SZ_GATES  ((unsigned long long)CM * P4 * 2)        // 134217728
#define OFF_EMBH  (OFF_GATES + SZ_GATES)
#define SZ_EMBH   (50257ull * 256 * 2)                     // 25731584
#define OFF_WX    (OFF_EMBH + SZ_EMBH)
#define SZ_WX     (1024ull * 256 * 2)
#define OFF_WH    (OFF_WX + SZ_WX)
#define SZ_WH     (1024ull * 256 * 2)
#define OFF_B4    (OFF_WH + SZ_WH)
#define SZ_B4     (1024ull * 4)
#define OFF_ST    (OFF_B4 + SZ_B4)
#define SZ_ST     (2ull * NB * DIM * 4)                    // h,c f32
#define WS_NEED   (OFF_ST + SZ_ST)                         // ~161.1 MB

// ---------------- helpers ----------------
__device__ __forceinline__ float sigm(float x) {
  x = fminf(fmaxf(x, -30.f), 30.f);
  return 1.f / (1.f + __expf(-x));
}
__device__ __forceinline__ float tanh_(float x) {
  x = fminf(fmaxf(x, -15.f), 15.f);
  float t = __expf(2.f * x);
  return (t - 1.f) / (t + 1.f);
}
__device__ __forceinline__ float dot8(half8_t w, half8_t h, float acc) {
  acc = __builtin_amdgcn_fdot2((half2_t)__builtin_shufflevector(w, w, 0, 1),
                               (half2_t)__builtin_shufflevector(h, h, 0, 1), acc, false);
  acc = __builtin_amdgcn_fdot2((half2_t)__builtin_shufflevector(w, w, 2, 3),
                               (half2_t)__builtin_shufflevector(h, h, 2, 3), acc, false);
  acc = __builtin_amdgcn_fdot2((half2_t)__builtin_shufflevector(w, w, 4, 5),
                               (half2_t)__builtin_shufflevector(h, h, 4, 5), acc, false);
  acc = __builtin_amdgcn_fdot2((half2_t)__builtin_shufflevector(w, w, 6, 7),
                               (half2_t)__builtin_shufflevector(h, h, 6, 7), acc, false);
  return acc;
}

// ---------------- kernels ----------------
__global__ void ws_too_small_kernel(float* out, float sz) {
  if (threadIdx.x == 0 && blockIdx.x == 0) out[0] = sz;
}

__global__ void cvt_emb_kernel(const float* __restrict__ src, half_t* __restrict__ dst,
                               int total8) {
  int i = blockIdx.x * blockDim.x + threadIdx.x;
  if (i >= total8) return;
  const float4* s = (const float4*)src + (size_t)i * 2;
  float4 a = s[0], b = s[1];
  half8_t o;
  o[0] = (half_t)a.x; o[1] = (half_t)a.y; o[2] = (half_t)a.z; o[3] = (half_t)a.w;
  o[4] = (half_t)b.x; o[5] = (half_t)b.y; o[6] = (half_t)b.z; o[7] = (half_t)b.w;
  *((half8_t*)dst + i) = o;
}

// Wx4h[p][k] row-major fp16 (p = gate*256+h, k = d)
// Wh4c[(k>>3)][p][k&7] fp16 (16B chunk per (k-chunk, p); lane-coalesced)
// b4[p] = b_input[p] + b_hidden[p]
__global__ void pack_w_kernel(const float* __restrict__ Wii, const float* __restrict__ Whi,
                              const float* __restrict__ Wif, const float* __restrict__ Whf,
                              const float* __restrict__ Wig, const float* __restrict__ Whg,
                              const float* __restrict__ Wio, const float* __restrict__ Who,
                              const float* __restrict__ bii, const float* __restrict__ bhi,
                              const float* __restrict__ bif, const float* __restrict__ bhf,
                              const float* __restrict__ big_, const float* __restrict__ bhg,
                              const float* __restrict__ bio, const float* __restrict__ bho,
                              half_t* __restrict__ Wx4h, half_t* __restrict__ Wh4c,
                              float* __restrict__ b4) {
  int p = blockIdx.x;   // 0..1023
  int k = threadIdx.x;  // 0..255
  int g = p >> 8, h = p & 255;
  const float* Wx = g == 0 ? Wii : g == 1 ? Wif : g == 2 ? Wig : Wio;
  const float* Wh = g == 0 ? Whi : g == 1 ? Whf : g == 2 ? Whg : Who;
  Wx4h[(size_t)p * DIM + k] = (half_t)Wx[h * DIM + k];
  Wh4c[((size_t)(k >> 3) * P4 + p) * 8 + (k & 7)] = (half_t)Wh[h * DIM + k];
  if (k == 0) {
    const float* bx = g == 0 ? bii : g == 1 ? bif : g == 2 ? big_ : bio;
    const float* bh = g == 0 ? bhi : g == 1 ? bhf : g == 2 ? bhg : bho;
    b4[p] = bx[h] + bh[h];
  }
}

// Phase A GEMM: gates[CM][P4] = gather(embh, xc)[CM][256] @ Wx4h^T + b4
// 128x128 tile, BK=32, 4 waves (2x2 of 64x64), mfma_f32_16x16x32_f16.
#define BK   32
#define LSTR 40  // LDS row stride in halfs
__global__ __launch_bounds__(256) void gemm_gates_kernel(
    const half_t* __restrict__ embh, const int* __restrict__ xc,
    const half_t* __restrict__ Wx4h, const float* __restrict__ b4,
    half_t* __restrict__ gates) {
  __shared__ __align__(16) half_t As[128 * LSTR];
  __shared__ __align__(16) half_t Ws[128 * LSTR];
  const int tid  = threadIdx.x;
  const int lane = tid & 63;
  const int wave = tid >> 6;
  const int wm = wave >> 1, wn = wave & 1;
  const int M0 = blockIdx.x * 128;
  const int P0 = blockIdx.y * 128;
  const int r0 = tid >> 2, s0 = tid & 3;  // staging: 2 rows/thread, 16B seg each

  const size_t arow0 = (size_t)xc[M0 + r0] * DIM;
  const size_t arow1 = (size_t)xc[M0 + 64 + r0] * DIM;
  const size_t wrow0 = (size_t)(P0 + r0) * DIM;
  const size_t wrow1 = (size_t)(P0 + 64 + r0) * DIM;

  f32x4 acc[4][4] = {};
  const int fr = lane & 15;    // fragment row/col within 16x16
  const int kq = lane >> 4;    // k-quarter: k = kq*8 + j

  for (int kt = 0; kt < 8; ++kt) {
    const int k0 = kt * BK;
    half8_t a0 = *(const half8_t*)(embh + arow0 + k0 + s0 * 8);
    half8_t a1 = *(const half8_t*)(embh + arow1 + k0 + s0 * 8);
    half8_t w0 = *(const half8_t*)(Wx4h + wrow0 + k0 + s0 * 8);
    half8_t w1 = *(const half8_t*)(Wx4h + wrow1 + k0 + s0 * 8);
    __syncthreads();  // previous iter's LDS reads complete
    *(half8_t*)(As + r0 * LSTR + s0 * 8)        = a0;
    *(half8_t*)(As + (r0 + 64) * LSTR + s0 * 8) = a1;
    *(half8_t*)(Ws + r0 * LSTR + s0 * 8)        = w0;
    *(half8_t*)(Ws + (r0 + 64) * LSTR + s0 * 8) = w1;
    __syncthreads();
    half8_t af[4], bf[4];
#pragma unroll
    for (int mi = 0; mi < 4; ++mi)
      af[mi] = *(const half8_t*)(As + (wm * 64 + mi * 16 + fr) * LSTR + kq * 8);
#pragma unroll
    for (int ni = 0; ni < 4; ++ni)
      bf[ni] = *(const half8_t*)(Ws + (wn * 64 + ni * 16 + fr) * LSTR + kq * 8);
#pragma unroll
    for (int mi = 0; mi < 4; ++mi)
#pragma unroll
      for (int ni = 0; ni < 4; ++ni)
        acc[mi][ni] = __builtin_amdgcn_mfma_f32_16x16x32_f16(af[mi], bf[ni], acc[mi][ni], 0, 0, 0);
  }
  // D layout: col = lane&15, row = 4*(lane>>4) + r   [m89-verified]
  const int rbase = (lane >> 4) * 4;
#pragma unroll
  for (int ni = 0; ni < 4; ++ni) {
    const int p = P0 + wn * 64 + ni * 16 + fr;
    const float bias = b4[p];
#pragma unroll
    for (int mi = 0; mi < 4; ++mi) {
      const int m = M0 + wm * 64 + mi * 16 + rbase;
#pragma unroll
      for (int r = 0; r < 4; ++r)
        gates[(size_t)(m + r) * P4 + p] = (half_t)(acc[mi][ni][r] + bias);
    }
  }
}

// Phase B: one block per chain n. 512 threads: j = tid&255 (hidden unit),
// kh = tid>>8 splits the K=256 dot 2-way (thread k-range = [kh*128, kh*128+128)).
// Per-thread weights (64 x half8): relative kc 0..11 pinned in VGPRs (192),
// relative kc 12..15 in LDS (128 KB). No per-step global weight traffic.
// Gate prefetch is owned by the kh==1 half and folded into its partials.
__global__ __launch_bounds__(512, 2) void lstm_kernel(
    const half_t* __restrict__ gates, const half_t* __restrict__ Wh4c,
    const float* __restrict__ Wout, const float* __restrict__ bout,
    float* __restrict__ out, float* __restrict__ state,
    int first, int last) {
  const int n   = blockIdx.x;
  const int tid = threadIdx.x;
  const int j   = tid & 255;
  const int kh  = tid >> 8;
  __shared__ __align__(16) half_t wlds[8][P4][8];   // 128 KB weight cache
  __shared__ __align__(16) half_t hbuf[2][DIM];
  __shared__ __align__(16) float  partial4[DIM][4]; // 4 KB
  __shared__ float hfin[DIM];

  const half8_t* W8 = (const half8_t*)Wh4c;
  // LDS cache: slot s holds absolute kc = (s>>2)*16 + 12 + (s&3)  (12..15 / 28..31)
  for (int i = tid; i < 8192; i += 512) {
    const int slot = i >> 10, p = i & 1023;
    const int kc = (slot >> 2) * 16 + 12 + (slot & 3);
    *(half8_t*)wlds[slot][p] = W8[kc * P4 + p];
  }
  const int kc0 = kh * 16;
  const int b0 = j, b1 = 256 + j, b2 = 512 + j, b3 = 768 + j;
  // register-resident weights: this thread's relative kc 0..11 (192 VGPRs)
  half8_t wreg[12][4];
#pragma unroll
  for (int kc = 0; kc < 12; ++kc) {
    wreg[kc][0] = W8[(kc0 + kc) * P4 + b0];
    wreg[kc][1] = W8[(kc0 + kc) * P4 + b1];
    wreg[kc][2] = W8[(kc0 + kc) * P4 + b2];
    wreg[kc][3] = W8[(kc0 + kc) * P4 + b3];
  }
  // Pin: opaque def/use so the compiler cannot sink these loads into the
  // loop (round-2 VGPR=120 proved it had been re-streaming them from L2).
#pragma unroll
  for (int kc = 0; kc < 12; ++kc)
#pragma unroll
    for (int g = 0; g < 4; ++g)
      asm volatile("" : "+v"(wreg[kc][g]));

  float c = 0.f, hkeep = 0.f;
  if (kh == 0) {
    float h0 = 0.f;
    if (!first) { h0 = state[n * DIM + j]; c = state[NB * DIM + n * DIM + j]; }
    hbuf[0][j] = (half_t)h0;
    hkeep = h0;
  }
  // gates prefetch (owned by kh==1, folded into its partial sums)
  const half_t* gbase = gates + (size_t)n * P4;
  float g0 = 0.f, g1 = 0.f, g2 = 0.f, g3 = 0.f;
  if (kh == 1) {
    g0 = (float)gbase[b0]; g1 = (float)gbase[b1];
    g2 = (float)gbase[b2]; g3 = (float)gbase[b3];
  }
  __syncthreads();

#pragma unroll 1
  for (int l = 0; l < CHUNK_L; ++l) {
    float a0 = 0.f, a1 = 0.f, a2 = 0.f, a3 = 0.f;
    half_t ng0, ng1, ng2, ng3;
    if (kh == 1) {
      a0 = g0; a1 = g1; a2 = g2; a3 = g3;
      // issue next step's gate loads now (latency hidden under the dots;
      // last-iter read lands in embh region of ws - harmless)
      const half_t* gp2 = gbase + (size_t)(l + 1) * NB * P4;
      ng0 = gp2[b0]; ng1 = gp2[b1]; ng2 = gp2[b2]; ng3 = gp2[b3];
    }
    const half8_t* hp = (const half8_t*)hbuf[l & 1] + kc0;
    // registers: relative kc 0..11
#pragma unroll
    for (int kc = 0; kc < 12; ++kc) {
      const half8_t h8 = hp[kc];
      a0 = dot8(wreg[kc][0], h8, a0);
      a1 = dot8(wreg[kc][1], h8, a1);
      a2 = dot8(wreg[kc][2], h8, a2);
      a3 = dot8(wreg[kc][3], h8, a3);
    }
    // LDS: relative kc 12..15
#pragma unroll
    for (int s = 0; s < 4; ++s) {
      const half8_t h8 = hp[12 + s];
      const int slot = kh * 4 + s;
      a0 = dot8(*(const half8_t*)wlds[slot][b0], h8, a0);
      a1 = dot8(*(const half8_t*)wlds[slot][b1], h8, a1);
      a2 = dot8(*(const half8_t*)wlds[slot][b2], h8, a2);
      a3 = dot8(*(const half8_t*)wlds[slot][b3], h8, a3);
    }
    if (kh == 1) {
      float4 pv; pv.x = a0; pv.y = a1; pv.z = a2; pv.w = a3;
      *(float4*)partial4[j] = pv;
      g0 = (float)ng0; g1 = (float)ng1; g2 = (float)ng2; g3 = (float)ng3;
    }
    __syncthreads();
    if (kh == 0) {
      float4 pv = *(const float4*)partial4[j];
      a0 += pv.x; a1 += pv.y; a2 += pv.z; a3 += pv.w;
      const float it = sigm(a0), ft = sigm(a1), gt = tanh_(a2), ot = sigm(a3);
      c = ft * c + it * gt;
      const float h = ot * tanh_(c);
      hbuf[(l + 1) & 1][j] = (half_t)h;
      hkeep = h;
    }
    __syncthreads();
  }
  if (kh == 0) {
    if (!last) { state[n * DIM + j] = hkeep; state[NB * DIM + n * DIM + j] = c; }
    hfin[j] = hkeep;
  }
  __syncthreads();
  if (last && tid < 10) {
    float s = bout[tid];
    const float* wrow = Wout + tid * DIM;
#pragma unroll 4
    for (int k = 0; k < DIM; ++k) s += hfin[k] * wrow[k];
    out[n * 10 + tid] = s;
  }
}

// ---------------- launch ----------------
extern "C" void kernel_launch(void* const* d_in, const int* in_sizes, int n_in,
                              void* d_out, int out_size, void* d_ws, size_t ws_size,
                              hipStream_t stream) {
  const int*   x    = (const int*)d_in[0];
  const float* emb  = (const float*)d_in[1];
  const float* Wii  = (const float*)d_in[2];  const float* bii = (const float*)d_in[3];
  const float* Whi  = (const float*)d_in[4];  const float* bhi = (const float*)d_in[5];
  const float* Wif  = (const float*)d_in[6];  const float* bif = (const float*)d_in[7];
  const float* Whf  = (const float*)d_in[8];  const float* bhf = (const float*)d_in[9];
  const float* Wig  = (const float*)d_in[10]; const float* big_ = (const float*)d_in[11];
  const float* Whg  = (const float*)d_in[12]; const float* bhg = (const float*)d_in[13];
  const float* Wio  = (const float*)d_in[14]; const float* bio = (const float*)d_in[15];
  const float* Who  = (const float*)d_in[16]; const float* bho = (const float*)d_in[17];
  const float* Wout = (const float*)d_in[18]; const float* bout = (const float*)d_in[19];
  float* out = (float*)d_out;

  if (ws_size < WS_NEED) {  // fail loudly but safely: absmax will show ws_size
    hipLaunchKernelGGL(ws_too_small_kernel, dim3(1), dim3(64), 0, stream, out, (float)ws_size);
    return;
  }
  char* ws = (char*)d_ws;
  half_t* gates = (half_t*)(ws + OFF_GATES);
  half_t* embh  = (half_t*)(ws + OFF_EMBH);
  half_t* Wx4h  = (half_t*)(ws + OFF_WX);
  half_t* Wh4c  = (half_t*)(ws + OFF_WH);
  float*  b4    = (float*)(ws + OFF_B4);
  float*  state = (float*)(ws + OFF_ST);

  const int total8 = 50257 * 32;  // V*D/8
  hipLaunchKernelGGL(cvt_emb_kernel, dim3((total8 + 255) / 256), dim3(256), 0, stream,
                     emb, embh, total8);
  hipLaunchKernelGGL(pack_w_kernel, dim3(1024), dim3(256), 0, stream,
                     Wii, Whi, Wif, Whf, Wig, Whg, Wio, Who,
                     bii, bhi, bif, bhf, big_, bhg, bio, bho,
                     Wx4h, Wh4c, b4);
  // chunk 0: steps [0, 1024)
  hipLaunchKernelGGL(gemm_gates_kernel, dim3(CM / 128, P4 / 128), dim3(256), 0, stream,
                     embh, x, Wx4h, b4, gates);
  hipLaunchKernelGGL(lstm_kernel, dim3(NB), dim3(512), 0, stream,
                     gates, Wh4c, Wout, bout, out, state, 1, 0);
  // chunk 1: steps [1024, 2048)
  hipLaunchKernelGGL(gemm_gates_kernel, dim3(CM / 128, P4 / 128), dim3(256), 0, stream,
                     embh, x + (size_t)CHUNK_L * NB, Wx4h, b4, gates);
  hipLaunchKernelGGL(lstm_kernel, dim3(NB), dim3(512), 0, stream,
                     gates, Wh4c, Wout, bout, out, state, 0, 1);
}